// Round 1
// baseline (521.639 us; speedup 1.0000x reference)
//
#include <hip/hip_runtime.h>
#include <hip/hip_bf16.h>

#define BB 2
#define CC 512
#define NNP 4096
#define NH 8
#define HD 64
#define EPSV 1e-5f
#define SCALE 0.125f

typedef __bf16 bf16x8 __attribute__((ext_vector_type(8)));
typedef __bf16 bf16x4 __attribute__((ext_vector_type(4)));
typedef float f32x4 __attribute__((ext_vector_type(4)));

#define MFMA(a, b, c) __builtin_amdgcn_mfma_f32_16x16x32_bf16(a, b, c, 0, 0, 0)

#define GL2LDS(g, l)                                                            \
  __builtin_amdgcn_global_load_lds(                                             \
      (const __attribute__((address_space(1))) void*)(g),                       \
      (__attribute__((address_space(3))) void*)(l), 16, 0, 0)

// ---------------- weight fp32 -> bf16 ----------------
__global__ __launch_bounds__(256) void cvt_kernel(const float* __restrict__ qw,
                                                  const float* __restrict__ pw,
                                                  __bf16* __restrict__ dq,
                                                  __bf16* __restrict__ dp) {
  int i = blockIdx.x * 256 + threadIdx.x;
  const int NQ = 3 * CC * CC / 4;  // 196608 float4s of qkv_w
  float4 f;
  __bf16* d;
  if (i < NQ) {
    f = ((const float4*)qw)[i];
    d = dq + (size_t)i * 4;
  } else {
    int j = i - NQ;
    f = ((const float4*)pw)[j];
    d = dp + (size_t)j * 4;
  }
  bf16x4 o = {(__bf16)f.x, (__bf16)f.y, (__bf16)f.z, (__bf16)f.w};
  *(bf16x4*)d = o;
}

// ---------------- GroupNorm -> h^T (B*N, C) bf16 ----------------
__global__ __launch_bounds__(256) void gn_kernel(const float* __restrict__ x,
                                                 const float* __restrict__ gw,
                                                 const float* __restrict__ gb,
                                                 __bf16* __restrict__ h_t) {
  const int blk = blockIdx.x;  // B*32
  const int b = blk >> 5, g = blk & 31;
  const float* xg = x + ((size_t)b * CC + g * 16) * NNP;
  const int tid = threadIdx.x;
  float s = 0.f, ss = 0.f;
  const float4* x4 = (const float4*)xg;
#pragma unroll 4
  for (int i = tid; i < 16 * NNP / 4; i += 256) {
    float4 f = x4[i];
    s += f.x + f.y + f.z + f.w;
    ss += f.x * f.x + f.y * f.y + f.z * f.z + f.w * f.w;
  }
#pragma unroll
  for (int off = 1; off < 64; off <<= 1) {
    s += __shfl_xor(s, off);
    ss += __shfl_xor(ss, off);
  }
  __shared__ float red[8];
  const int wid = tid >> 6;
  if ((tid & 63) == 0) {
    red[wid] = s;
    red[4 + wid] = ss;
  }
  __syncthreads();
  s = red[0] + red[1] + red[2] + red[3];
  ss = red[4] + red[5] + red[6] + red[7];
  const float cnt = 1.f / (16.f * NNP);
  const float mean = s * cnt;
  const float var = ss * cnt - mean * mean;
  const float inv = rsqrtf(var + EPSV);
  float wv[16], bv[16];
#pragma unroll
  for (int c = 0; c < 16; ++c) {
    wv[c] = gw[g * 16 + c] * inv;
    bv[c] = gb[g * 16 + c] - mean * wv[c];
  }
  for (int it = 0; it < 16; ++it) {
    int n = tid + it * 256;
    __bf16* dst = h_t + ((size_t)b * NNP + n) * CC + g * 16;
    bf16x8 t0, t1;
#pragma unroll
    for (int c = 0; c < 8; ++c) t0[c] = (__bf16)(xg[(size_t)c * NNP + n] * wv[c] + bv[c]);
#pragma unroll
    for (int c = 8; c < 16; ++c) t1[c - 8] = (__bf16)(xg[(size_t)c * NNP + n] * wv[c] + bv[c]);
    *(bf16x8*)dst = t0;
    *(bf16x8*)(dst + 8) = t1;
  }
}

// ---------------- GEMM: C[o][bn] = sum_c A[o][c]*Bm[bn][c]  (both K-contig) ----
// MODE 0: qkv  -> scatter q^T,k^T (n-major) and v (d-major), +bias
// MODE 1: proj -> d_out = acc + bias + x (residual)
template <int MODE>
__global__ __launch_bounds__(256) void gemm_kernel(
    const __bf16* __restrict__ A, const __bf16* __restrict__ Bm,
    const float* __restrict__ bias, const float* __restrict__ xres,
    __bf16* __restrict__ q_t, __bf16* __restrict__ k_t, __bf16* __restrict__ v,
    float* __restrict__ outp) {
  __shared__ __bf16 sA[128 * 64];
  __shared__ __bf16 sB[128 * 64];
  const int tid = threadIdx.x;
  const int lane = tid & 63;
  const int wid = tid >> 6;
  const int wm = wid >> 1, wn = wid & 1;
  const int row_a = blockIdx.x * 128, row_b = blockIdx.y * 128;
  const int l15 = lane & 15, lg = lane >> 4;
  f32x4 acc[4][4] = {};
  const int sr = tid >> 3;  // 0..31 (row within 32-row staging slab)
  const int sc = tid & 7;   // 16B chunk (physical)
  for (int k0 = 0; k0 < CC; k0 += 64) {
#pragma unroll
    for (int j = 0; j < 4; ++j) {
      int r = j * 32 + sr;
      int cl = sc ^ (r & 7);  // inverse-swizzled SOURCE, linear LDS dest (rule 21)
      GL2LDS(A + (size_t)(row_a + r) * CC + k0 + cl * 8, sA + j * 2048 + tid * 8);
      GL2LDS(Bm + (size_t)(row_b + r) * CC + k0 + cl * 8, sB + j * 2048 + tid * 8);
    }
    __syncthreads();
#pragma unroll
    for (int kk = 0; kk < 2; ++kk) {
      bf16x8 af[4], bq[4];
#pragma unroll
      for (int i = 0; i < 4; ++i) {
        int ra = wm * 64 + i * 16 + l15;
        int ca = kk * 4 + lg;
        af[i] = *(const bf16x8*)&sA[ra * 64 + ((ca ^ (ra & 7)) * 8)];
        int rb = wn * 64 + i * 16 + l15;
        bq[i] = *(const bf16x8*)&sB[rb * 64 + ((ca ^ (rb & 7)) * 8)];
      }
#pragma unroll
      for (int mi = 0; mi < 4; ++mi)
#pragma unroll
        for (int nj = 0; nj < 4; ++nj)
          acc[mi][nj] = MFMA(af[mi], bq[nj], acc[mi][nj]);
    }
    __syncthreads();
  }
#pragma unroll
  for (int mi = 0; mi < 4; ++mi) {
    const int o0 = row_a + wm * 64 + mi * 16 + (lg << 2);
    float b4[4];
#pragma unroll
    for (int r = 0; r < 4; ++r) b4[r] = bias[o0 + r];
#pragma unroll
    for (int nj = 0; nj < 4; ++nj) {
      const int bn = row_b + wn * 64 + nj * 16 + l15;
      const int b_ = bn >> 12, n_ = bn & 4095;
      if constexpr (MODE == 0) {
        const int which = o0 >> 9, hh = (o0 >> 6) & 7, d0 = o0 & 63;
        if (which < 2) {
          __bf16* dst = (which ? k_t : q_t) + (((size_t)b_ * NH + hh) * NNP + n_) * HD + d0;
          bf16x4 pk;
#pragma unroll
          for (int r = 0; r < 4; ++r) pk[r] = (__bf16)(acc[mi][nj][r] + b4[r]);
          *(bf16x4*)dst = pk;
        } else {
#pragma unroll
          for (int r = 0; r < 4; ++r)
            v[(((size_t)b_ * NH + hh) * HD + d0 + r) * NNP + n_] =
                (__bf16)(acc[mi][nj][r] + b4[r]);
        }
      } else {
        const size_t base = ((size_t)b_ * CC + o0) * NNP + n_;
#pragma unroll
        for (int r = 0; r < 4; ++r)
          outp[base + (size_t)r * NNP] = acc[mi][nj][r] + b4[r] + xres[base + (size_t)r * NNP];
      }
    }
  }
}

// ---------------- flash attention (swapped QK^T) ----------------
// block = (b,h, 64-query tile); wave owns 16 queries. S^T = mfma(K,Q):
// lane col = n, rows = m -> softmax over m = in-lane + shfl 16/32.
// P^T -> per-wave swizzled LDS tile -> PV B-operand; A = V direct from global.
__global__ __launch_bounds__(256) void attn_kernel(const __bf16* __restrict__ q_t,
                                                   const __bf16* __restrict__ k_t,
                                                   const __bf16* __restrict__ vm,
                                                   __bf16* __restrict__ o_t) {
  const int blk = blockIdx.x;  // B*NH*64
  const int qt = blk & 63, bh = blk >> 6;
  const int tid = threadIdx.x, lane = tid & 63, wid = tid >> 6;
  const int l15 = lane & 15, lg = lane >> 4;
  const int n0 = qt * 64 + wid * 16;
  const __bf16* qp = q_t + ((size_t)bh * NNP + n0) * HD;
  const __bf16* kp = k_t + (size_t)bh * NNP * HD;
  const __bf16* vp = vm + (size_t)bh * HD * NNP;
  bf16x8 qf[2];
#pragma unroll
  for (int kk = 0; kk < 2; ++kk) qf[kk] = *(const bf16x8*)&qp[l15 * HD + kk * 32 + lg * 8];
  f32x4 oacc[4] = {};
  float mrow = -3.0e38f, lrow = 0.f;
  __shared__ __bf16 plds[4][16 * 64];
  __bf16* pl = &plds[wid][0];
  for (int m0 = 0; m0 < NNP; m0 += 64) {
    f32x4 sfr[4];
#pragma unroll
    for (int ms = 0; ms < 4; ++ms) {
      f32x4 z = {0.f, 0.f, 0.f, 0.f};
#pragma unroll
      for (int kk = 0; kk < 2; ++kk) {
        bf16x8 kf = *(const bf16x8*)&kp[(size_t)(m0 + ms * 16 + l15) * HD + kk * 32 + lg * 8];
        z = MFMA(kf, qf[kk], z);
      }
      sfr[ms] = z;
    }
    float tmax = -3.0e38f;
#pragma unroll
    for (int ms = 0; ms < 4; ++ms)
#pragma unroll
      for (int r = 0; r < 4; ++r) {
        sfr[ms][r] *= SCALE;
        tmax = fmaxf(tmax, sfr[ms][r]);
      }
    tmax = fmaxf(tmax, __shfl_xor(tmax, 16));
    tmax = fmaxf(tmax, __shfl_xor(tmax, 32));
    const float mnew = fmaxf(mrow, tmax);
    const float alpha = __expf(mrow - mnew);
    float psum = 0.f;
#pragma unroll
    for (int ms = 0; ms < 4; ++ms) {
      bf16x4 pk;
#pragma unroll
      for (int r = 0; r < 4; ++r) {
        float p = __expf(sfr[ms][r] - mnew);
        psum += p;
        pk[r] = (__bf16)p;
      }
      // P^T[m][n] -> LDS row n, m-bytes XOR-swizzled per 16B chunk
      int cl16 = ms * 2 + (lg >> 1);
      int phys = l15 * 128 + ((cl16 ^ (l15 & 7)) * 16) + (lg & 1) * 8;
      *(bf16x4*)((char*)pl + phys) = pk;
    }
    psum += __shfl_xor(psum, 16);
    psum += __shfl_xor(psum, 32);
    lrow = lrow * alpha + psum;
    mrow = mnew;
#pragma unroll
    for (int ds = 0; ds < 4; ++ds)
#pragma unroll
      for (int r = 0; r < 4; ++r) oacc[ds][r] *= alpha;
#pragma unroll
    for (int kk2 = 0; kk2 < 2; ++kk2) {
      int cl16 = kk2 * 4 + lg;
      bf16x8 pf = *(const bf16x8*)((const char*)pl + l15 * 128 + ((cl16 ^ (l15 & 7)) * 16));
#pragma unroll
      for (int ds = 0; ds < 4; ++ds) {
        bf16x8 vf =
            *(const bf16x8*)&vp[(size_t)(ds * 16 + l15) * NNP + m0 + kk2 * 32 + lg * 8];
        oacc[ds] = MFMA(vf, pf, oacc[ds]);
      }
    }
  }
  const float invl = 1.f / lrow;
  const int b_ = bh >> 3, hh = bh & 7;
  __bf16* op = o_t + ((size_t)b_ * NNP + n0 + l15) * CC + hh * HD;
#pragma unroll
  for (int ds = 0; ds < 4; ++ds) {
    bf16x4 pk;
#pragma unroll
    for (int r = 0; r < 4; ++r) pk[r] = (__bf16)(oacc[ds][r] * invl);
    *(bf16x4*)(op + ds * 16 + lg * 4) = pk;
  }
}

extern "C" void kernel_launch(void* const* d_in, const int* in_sizes, int n_in,
                              void* d_out, int out_size, void* d_ws, size_t ws_size,
                              hipStream_t stream) {
  const float* x = (const float*)d_in[0];
  const float* gn_w = (const float*)d_in[1];
  const float* gn_b = (const float*)d_in[2];
  const float* qkv_w = (const float*)d_in[3];
  const float* qkv_b = (const float*)d_in[4];
  const float* proj_w = (const float*)d_in[5];
  const float* proj_b = (const float*)d_in[6];
  float* out = (float*)d_out;
  char* ws = (char*)d_ws;
  const size_t SZ = (size_t)BB * NNP * CC * 2;  // 8 MiB per bf16 (B,N,C) tensor
  __bf16* h_t = (__bf16*)(ws);
  __bf16* q_t = (__bf16*)(ws + SZ);
  __bf16* k_t = (__bf16*)(ws + 2 * SZ);
  __bf16* v = (__bf16*)(ws + 3 * SZ);
  __bf16* o_t = (__bf16*)(ws + 4 * SZ);
  __bf16* wq = (__bf16*)(ws + 5 * SZ);
  __bf16* wp = (__bf16*)(ws + 5 * SZ + (size_t)3 * CC * CC * 2);

  cvt_kernel<<<dim3(1024), dim3(256), 0, stream>>>(qkv_w, proj_w, wq, wp);
  gn_kernel<<<dim3(64), dim3(256), 0, stream>>>(x, gn_w, gn_b, h_t);
  gemm_kernel<0><<<dim3(12, 64), dim3(256), 0, stream>>>(wq, h_t, qkv_b, nullptr, q_t, k_t,
                                                         v, nullptr);
  attn_kernel<<<dim3(BB * NH * 64), dim3(256), 0, stream>>>(q_t, k_t, v, o_t);
  gemm_kernel<1><<<dim3(4, 64), dim3(256), 0, stream>>>(wp, o_t, proj_b, x, nullptr, nullptr,
                                                        nullptr, out);
}

// Round 3
// 323.801 us; speedup vs baseline: 1.6110x; 1.6110x over previous
//
#include <hip/hip_runtime.h>
#include <hip/hip_bf16.h>

#define BB 2
#define CC 512
#define NNP 4096
#define NH 8
#define HD 64
#define EPSV 1e-5f
// scale(1/8) * log2(e) folded into q at the QKV epilogue -> softmax uses exp2
#define QSCALE 0.18033688011112042f

typedef __bf16 bf16x8 __attribute__((ext_vector_type(8)));
typedef __bf16 bf16x4 __attribute__((ext_vector_type(4)));
typedef float f32x4 __attribute__((ext_vector_type(4)));
typedef float f32x16 __attribute__((ext_vector_type(16)));

#define MFMA(a, b, c) __builtin_amdgcn_mfma_f32_16x16x32_bf16(a, b, c, 0, 0, 0)
#define MFMA32(a, b, c) __builtin_amdgcn_mfma_f32_32x32x16_bf16(a, b, c, 0, 0, 0)

#define GL2LDS(g, l)                                                            \
  __builtin_amdgcn_global_load_lds(                                             \
      (const __attribute__((address_space(1))) void*)(g),                       \
      (__attribute__((address_space(3))) void*)(l), 16, 0, 0)

// pack two f32 -> two bf16 in a dword (low = first arg); plain casts so the
// compiler picks the instruction (m240: hand-asm cvt_pk is slower anyway).
__device__ __forceinline__ unsigned pkcast(float lo, float hi) {
  union {
    __bf16 h[2];
    unsigned u;
  } t;
  t.h[0] = (__bf16)lo;
  t.h[1] = (__bf16)hi;
  return t.u;
}

// ---------------- weight fp32 -> bf16 ----------------
__global__ __launch_bounds__(256) void cvt_kernel(const float* __restrict__ qw,
                                                  const float* __restrict__ pw,
                                                  __bf16* __restrict__ dq,
                                                  __bf16* __restrict__ dp) {
  int i = blockIdx.x * 256 + threadIdx.x;
  const int NQ = 3 * CC * CC / 4;
  float4 f;
  __bf16* d;
  if (i < NQ) {
    f = ((const float4*)qw)[i];
    d = dq + (size_t)i * 4;
  } else {
    int j = i - NQ;
    f = ((const float4*)pw)[j];
    d = dp + (size_t)j * 4;
  }
  bf16x4 o = {(__bf16)f.x, (__bf16)f.y, (__bf16)f.z, (__bf16)f.w};
  *(bf16x4*)d = o;
}

// ---------------- GroupNorm -> h^T (B*N, C) bf16 ----------------
__global__ __launch_bounds__(256) void gn_kernel(const float* __restrict__ x,
                                                 const float* __restrict__ gw,
                                                 const float* __restrict__ gb,
                                                 __bf16* __restrict__ h_t) {
  const int blk = blockIdx.x;  // B*32
  const int b = blk >> 5, g = blk & 31;
  const float* xg = x + ((size_t)b * CC + g * 16) * NNP;
  const int tid = threadIdx.x;
  float s = 0.f, ss = 0.f;
  const float4* x4 = (const float4*)xg;
#pragma unroll 4
  for (int i = tid; i < 16 * NNP / 4; i += 256) {
    float4 f = x4[i];
    s += f.x + f.y + f.z + f.w;
    ss += f.x * f.x + f.y * f.y + f.z * f.z + f.w * f.w;
  }
#pragma unroll
  for (int off = 1; off < 64; off <<= 1) {
    s += __shfl_xor(s, off);
    ss += __shfl_xor(ss, off);
  }
  __shared__ float red[8];
  const int wid = tid >> 6;
  if ((tid & 63) == 0) {
    red[wid] = s;
    red[4 + wid] = ss;
  }
  __syncthreads();
  s = red[0] + red[1] + red[2] + red[3];
  ss = red[4] + red[5] + red[6] + red[7];
  const float cnt = 1.f / (16.f * NNP);
  const float mean = s * cnt;
  const float var = ss * cnt - mean * mean;
  const float inv = rsqrtf(var + EPSV);
  float wv[16], bv[16];
#pragma unroll
  for (int c = 0; c < 16; ++c) {
    wv[c] = gw[g * 16 + c] * inv;
    bv[c] = gb[g * 16 + c] - mean * wv[c];
  }
  for (int it = 0; it < 16; ++it) {
    int n = tid + it * 256;
    __bf16* dst = h_t + ((size_t)b * NNP + n) * CC + g * 16;
    bf16x8 t0, t1;
#pragma unroll
    for (int c = 0; c < 8; ++c) t0[c] = (__bf16)(xg[(size_t)c * NNP + n] * wv[c] + bv[c]);
#pragma unroll
    for (int c = 8; c < 16; ++c) t1[c - 8] = (__bf16)(xg[(size_t)c * NNP + n] * wv[c] + bv[c]);
    *(bf16x8*)dst = t0;
    *(bf16x8*)(dst + 8) = t1;
  }
}

// ---------------- GEMM: C[o][bn] = sum_c A[o][c]*Bm[bn][c]  (both K-contig) ----
// MODE 0: qkv  -> scatter q^T (scaled), k^T (n-major) and v (d-major), +bias
// MODE 1: proj -> d_out = acc + bias + x (residual)
template <int MODE>
__global__ __launch_bounds__(256) void gemm_kernel(
    const __bf16* __restrict__ A, const __bf16* __restrict__ Bm,
    const float* __restrict__ bias, const float* __restrict__ xres,
    __bf16* __restrict__ q_t, __bf16* __restrict__ k_t, __bf16* __restrict__ v,
    float* __restrict__ outp) {
  __shared__ __bf16 sA[128 * 64];
  __shared__ __bf16 sB[128 * 64];
  const int tid = threadIdx.x;
  const int lane = tid & 63;
  const int wid = tid >> 6;
  const int wm = wid >> 1, wn = wid & 1;
  const int row_a = blockIdx.x * 128, row_b = blockIdx.y * 128;
  const int l15 = lane & 15, lg = lane >> 4;
  f32x4 acc[4][4] = {};
  const int sr = tid >> 3;
  const int sc = tid & 7;
  for (int k0 = 0; k0 < CC; k0 += 64) {
#pragma unroll
    for (int j = 0; j < 4; ++j) {
      int r = j * 32 + sr;
      int cl = sc ^ (r & 7);  // inverse-swizzled SOURCE, linear LDS dest
      GL2LDS(A + (size_t)(row_a + r) * CC + k0 + cl * 8, sA + j * 2048 + tid * 8);
      GL2LDS(Bm + (size_t)(row_b + r) * CC + k0 + cl * 8, sB + j * 2048 + tid * 8);
    }
    __syncthreads();
#pragma unroll
    for (int kk = 0; kk < 2; ++kk) {
      bf16x8 af[4], bq[4];
#pragma unroll
      for (int i = 0; i < 4; ++i) {
        int ra = wm * 64 + i * 16 + l15;
        int ca = kk * 4 + lg;
        af[i] = *(const bf16x8*)&sA[ra * 64 + ((ca ^ (ra & 7)) * 8)];
        int rb = wn * 64 + i * 16 + l15;
        bq[i] = *(const bf16x8*)&sB[rb * 64 + ((ca ^ (rb & 7)) * 8)];
      }
#pragma unroll
      for (int mi = 0; mi < 4; ++mi)
#pragma unroll
        for (int nj = 0; nj < 4; ++nj)
          acc[mi][nj] = MFMA(af[mi], bq[nj], acc[mi][nj]);
    }
    __syncthreads();
  }
#pragma unroll
  for (int mi = 0; mi < 4; ++mi) {
    const int o0 = row_a + wm * 64 + mi * 16 + (lg << 2);
    float b4[4];
#pragma unroll
    for (int r = 0; r < 4; ++r) b4[r] = bias[o0 + r];
#pragma unroll
    for (int nj = 0; nj < 4; ++nj) {
      const int bn = row_b + wn * 64 + nj * 16 + l15;
      const int b_ = bn >> 12, n_ = bn & 4095;
      if constexpr (MODE == 0) {
        const int which = o0 >> 9, hh = (o0 >> 6) & 7, d0 = o0 & 63;
        if (which < 2) {
          const float qs = (which == 0) ? QSCALE : 1.0f;
          __bf16* dst = (which ? k_t : q_t) + (((size_t)b_ * NH + hh) * NNP + n_) * HD + d0;
          bf16x4 pk;
#pragma unroll
          for (int r = 0; r < 4; ++r) pk[r] = (__bf16)((acc[mi][nj][r] + b4[r]) * qs);
          *(bf16x4*)dst = pk;
        } else {
#pragma unroll
          for (int r = 0; r < 4; ++r)
            v[(((size_t)b_ * NH + hh) * HD + d0 + r) * NNP + n_] =
                (__bf16)(acc[mi][nj][r] + b4[r]);
        }
      } else {
        const size_t base = ((size_t)b_ * CC + o0) * NNP + n_;
#pragma unroll
        for (int r = 0; r < 4; ++r)
          outp[base + (size_t)r * NNP] = acc[mi][nj][r] + b4[r] + xres[base + (size_t)r * NNP];
      }
    }
  }
}

// ---------------- flash attention, 32x32 swapped-QK, no LDS ----------------
// wave owns 32 queries (col n = lane&31). S^T = mfma32(K, Q): lane holds 16 of
// 32 m-values for its query (rows split with lane^32). Softmax in-register
// (exact per-tile max); P -> PV B-operand via bf16 pack + __shfl_xor(32);
// V is d-major (A-operand).
__global__ __launch_bounds__(256) void attn_kernel(const __bf16* __restrict__ q_t,
                                                   const __bf16* __restrict__ k_t,
                                                   const __bf16* __restrict__ vm,
                                                   __bf16* __restrict__ o_t) {
  const int blk = blockIdx.x;  // B*NH*32
  const int qt = blk & 31, bh = blk >> 5;
  const int tid = threadIdx.x, lane = tid & 63, wid = tid >> 6;
  const int l31 = lane & 31, hi = lane >> 5;
  const int n0 = qt * 128 + wid * 32;
  const __bf16* qp = q_t + ((size_t)bh * NNP + n0) * HD;
  const __bf16* kp = k_t + (size_t)bh * NNP * HD;
  const __bf16* vp = vm + (size_t)bh * HD * NNP;
  bf16x8 qf[4];  // B-operand: col n = l31, k = d = c*16 + hi*8 + j
#pragma unroll
  for (int c = 0; c < 4; ++c) qf[c] = *(const bf16x8*)&qp[l31 * HD + c * 16 + hi * 8];
  f32x16 oa0 = {}, oa1 = {};  // O^T tiles: d 0..31 / 32..63, col n = l31
  float mrow = -1e30f, lrow = 0.f;
  for (int m0 = 0; m0 < NNP; m0 += 64) {
    f32x16 s0 = {}, s1 = {};
#pragma unroll
    for (int c = 0; c < 4; ++c) {
      bf16x8 kf0 = *(const bf16x8*)&kp[(size_t)(m0 + l31) * HD + c * 16 + hi * 8];
      bf16x8 kf1 = *(const bf16x8*)&kp[(size_t)(m0 + 32 + l31) * HD + c * 16 + hi * 8];
      s0 = MFMA32(kf0, qf[c], s0);
      s1 = MFMA32(kf1, qf[c], s1);
    }
    // max over this tile-pair's 32 in-lane m-values + 32 in partner lane
    float mx[8];
#pragma unroll
    for (int r = 0; r < 8; ++r)
      mx[r] = fmaxf(fmaxf(s0[r], s0[r + 8]), fmaxf(s1[r], s1[r + 8]));
#pragma unroll
    for (int st = 4; st >= 1; st >>= 1)
#pragma unroll
      for (int r = 0; r < 4; ++r)
        if (r < st) mx[r] = fmaxf(mx[r], mx[r + st]);
    float tmax = mx[0];
    tmax = fmaxf(tmax, __shfl_xor(tmax, 32));
    // exact online-softmax rescale every tile (R1-proven numerics)
    const float mnew = fmaxf(mrow, tmax);
    const float alpha = exp2f(mrow - mnew);
    lrow *= alpha;
#pragma unroll
    for (int r = 0; r < 16; ++r) {
      oa0[r] *= alpha;
      oa1[r] *= alpha;
    }
    mrow = mnew;
    float psum = 0.f;
#pragma unroll
    for (int r = 0; r < 16; ++r) {
      s0[r] = exp2f(s0[r] - mrow);
      s1[r] = exp2f(s1[r] - mrow);
      psum += s0[r] + s1[r];
    }
    psum += __shfl_xor(psum, 32);
    lrow += psum;
    // pack P -> PV B-fragments (k-rows exchanged with lane^32 via shfl)
#pragma unroll
    for (int g = 0; g < 2; ++g) {  // S tile (m base = m0 + g*32)
      unsigned u[8], pu[8];
#pragma unroll
      for (int i = 0; i < 8; ++i) {
        float a = (g == 0) ? s0[2 * i] : s1[2 * i];
        float b = (g == 0) ? s0[2 * i + 1] : s1[2 * i + 1];
        u[i] = pkcast(a, b);  // rows (4hi + (i&1)*2 + 8*(i>>1)) pair
      }
#pragma unroll
      for (int i = 0; i < 8; ++i) pu[i] = (unsigned)__shfl_xor((int)u[i], 32);
      union U {
        unsigned u[4];
        bf16x8 v;
      };
      U pf0, pf1;
      // chunk mc=0: k = hi*8 + j -> tile rows hi?8..15:0..7
      pf0.u[0] = hi ? pu[2] : u[0];
      pf0.u[1] = hi ? pu[3] : u[1];
      pf0.u[2] = hi ? u[2] : pu[0];
      pf0.u[3] = hi ? u[3] : pu[1];
      // chunk mc=1: tile rows hi?24..31:16..23
      pf1.u[0] = hi ? pu[6] : u[4];
      pf1.u[1] = hi ? pu[7] : u[5];
      pf1.u[2] = hi ? u[6] : pu[4];
      pf1.u[3] = hi ? u[7] : pu[5];
#pragma unroll
      for (int mc = 0; mc < 2; ++mc) {
        const int mb = m0 + g * 32 + mc * 16 + hi * 8;
        bf16x8 pf = mc ? pf1.v : pf0.v;
        bf16x8 vf0 = *(const bf16x8*)&vp[(size_t)l31 * NNP + mb];
        bf16x8 vf1 = *(const bf16x8*)&vp[(size_t)(32 + l31) * NNP + mb];
        oa0 = MFMA32(vf0, pf, oa0);
        oa1 = MFMA32(vf1, pf, oa1);
      }
    }
  }
  const float invl = 1.f / lrow;
  const int b_ = bh >> 3, hh = bh & 7;
  __bf16* op = o_t + ((size_t)b_ * NNP + n0 + l31) * CC + hh * HD;
#pragma unroll
  for (int g = 0; g < 4; ++g) {  // d = 8g + 4hi + r (tile0), +32 (tile1)
    bf16x4 p0, p1;
#pragma unroll
    for (int r = 0; r < 4; ++r) {
      p0[r] = (__bf16)(oa0[4 * g + r] * invl);
      p1[r] = (__bf16)(oa1[4 * g + r] * invl);
    }
    *(bf16x4*)(op + 8 * g + 4 * hi) = p0;
    *(bf16x4*)(op + 32 + 8 * g + 4 * hi) = p1;
  }
}

extern "C" void kernel_launch(void* const* d_in, const int* in_sizes, int n_in,
                              void* d_out, int out_size, void* d_ws, size_t ws_size,
                              hipStream_t stream) {
  const float* x = (const float*)d_in[0];
  const float* gn_w = (const float*)d_in[1];
  const float* gn_b = (const float*)d_in[2];
  const float* qkv_w = (const float*)d_in[3];
  const float* qkv_b = (const float*)d_in[4];
  const float* proj_w = (const float*)d_in[5];
  const float* proj_b = (const float*)d_in[6];
  float* out = (float*)d_out;
  char* ws = (char*)d_ws;
  const size_t SZ = (size_t)BB * NNP * CC * 2;  // 8 MiB per bf16 (B,N,C) tensor
  __bf16* h_t = (__bf16*)(ws);
  __bf16* q_t = (__bf16*)(ws + SZ);
  __bf16* k_t = (__bf16*)(ws + 2 * SZ);
  __bf16* v = (__bf16*)(ws + 3 * SZ);
  __bf16* o_t = (__bf16*)(ws + 4 * SZ);
  __bf16* wq = (__bf16*)(ws + 5 * SZ);
  __bf16* wp = (__bf16*)(ws + 5 * SZ + (size_t)3 * CC * CC * 2);

  cvt_kernel<<<dim3(1024), dim3(256), 0, stream>>>(qkv_w, proj_w, wq, wp);
  gn_kernel<<<dim3(64), dim3(256), 0, stream>>>(x, gn_w, gn_b, h_t);
  gemm_kernel<0><<<dim3(12, 64), dim3(256), 0, stream>>>(wq, h_t, qkv_b, nullptr, q_t, k_t,
                                                         v, nullptr);
  attn_kernel<<<dim3(BB * NH * 32), dim3(256), 0, stream>>>(q_t, k_t, v, o_t);
  gemm_kernel<1><<<dim3(4, 64), dim3(256), 0, stream>>>(wp, o_t, proj_b, x, nullptr, nullptr,
                                                        nullptr, out);
}

// Round 4
// 300.892 us; speedup vs baseline: 1.7336x; 1.0761x over previous
//
#include <hip/hip_runtime.h>
#include <hip/hip_bf16.h>

#define BB 2
#define CC 512
#define NNP 4096
#define NH 8
#define HD 64
#define EPSV 1e-5f
// scale(1/8) * log2(e) folded into q at the QKV epilogue -> softmax uses exp2
#define QSCALE 0.18033688011112042f

typedef __bf16 bf16x8 __attribute__((ext_vector_type(8)));
typedef __bf16 bf16x4 __attribute__((ext_vector_type(4)));
typedef float f32x4 __attribute__((ext_vector_type(4)));
typedef float f32x16 __attribute__((ext_vector_type(16)));

#define MFMA(a, b, c) __builtin_amdgcn_mfma_f32_16x16x32_bf16(a, b, c, 0, 0, 0)
#define MFMA32(a, b, c) __builtin_amdgcn_mfma_f32_32x32x16_bf16(a, b, c, 0, 0, 0)

#define GL2LDS(g, l)                                                            \
  __builtin_amdgcn_global_load_lds(                                             \
      (const __attribute__((address_space(1))) void*)(g),                       \
      (__attribute__((address_space(3))) void*)(l), 16, 0, 0)

// pack two f32 -> two bf16 in a dword (low = first arg)
__device__ __forceinline__ unsigned pkcast(float lo, float hi) {
  union {
    __bf16 h[2];
    unsigned u;
  } t;
  t.h[0] = (__bf16)lo;
  t.h[1] = (__bf16)hi;
  return t.u;
}

// ---------------- weight fp32 -> bf16 ----------------
__global__ __launch_bounds__(256) void cvt_kernel(const float* __restrict__ qw,
                                                  const float* __restrict__ pw,
                                                  __bf16* __restrict__ dq,
                                                  __bf16* __restrict__ dp) {
  int i = blockIdx.x * 256 + threadIdx.x;
  const int NQ = 3 * CC * CC / 4;
  float4 f;
  __bf16* d;
  if (i < NQ) {
    f = ((const float4*)qw)[i];
    d = dq + (size_t)i * 4;
  } else {
    int j = i - NQ;
    f = ((const float4*)pw)[j];
    d = dp + (size_t)j * 4;
  }
  bf16x4 o = {(__bf16)f.x, (__bf16)f.y, (__bf16)f.z, (__bf16)f.w};
  *(bf16x4*)d = o;
}

// ---------------- GroupNorm -> h^T (B*N, C) bf16 ----------------
__global__ __launch_bounds__(256) void gn_kernel(const float* __restrict__ x,
                                                 const float* __restrict__ gw,
                                                 const float* __restrict__ gb,
                                                 __bf16* __restrict__ h_t) {
  const int blk = blockIdx.x;  // B*32
  const int b = blk >> 5, g = blk & 31;
  const float* xg = x + ((size_t)b * CC + g * 16) * NNP;
  const int tid = threadIdx.x;
  float s = 0.f, ss = 0.f;
  const float4* x4 = (const float4*)xg;
#pragma unroll 4
  for (int i = tid; i < 16 * NNP / 4; i += 256) {
    float4 f = x4[i];
    s += f.x + f.y + f.z + f.w;
    ss += f.x * f.x + f.y * f.y + f.z * f.z + f.w * f.w;
  }
#pragma unroll
  for (int off = 1; off < 64; off <<= 1) {
    s += __shfl_xor(s, off);
    ss += __shfl_xor(ss, off);
  }
  __shared__ float red[8];
  const int wid = tid >> 6;
  if ((tid & 63) == 0) {
    red[wid] = s;
    red[4 + wid] = ss;
  }
  __syncthreads();
  s = red[0] + red[1] + red[2] + red[3];
  ss = red[4] + red[5] + red[6] + red[7];
  const float cnt = 1.f / (16.f * NNP);
  const float mean = s * cnt;
  const float var = ss * cnt - mean * mean;
  const float inv = rsqrtf(var + EPSV);
  float wv[16], bv[16];
#pragma unroll
  for (int c = 0; c < 16; ++c) {
    wv[c] = gw[g * 16 + c] * inv;
    bv[c] = gb[g * 16 + c] - mean * wv[c];
  }
  for (int it = 0; it < 16; ++it) {
    int n = tid + it * 256;
    __bf16* dst = h_t + ((size_t)b * NNP + n) * CC + g * 16;
    bf16x8 t0, t1;
#pragma unroll
    for (int c = 0; c < 8; ++c) t0[c] = (__bf16)(xg[(size_t)c * NNP + n] * wv[c] + bv[c]);
#pragma unroll
    for (int c = 8; c < 16; ++c) t1[c - 8] = (__bf16)(xg[(size_t)c * NNP + n] * wv[c] + bv[c]);
    *(bf16x8*)dst = t0;
    *(bf16x8*)(dst + 8) = t1;
  }
}

// ---------------- GEMM: C[o][bn] = sum_c A[o][c]*Bm[bn][c]  (both K-contig) ----
// MODE 0: qkv  -> scatter q^T (scaled), k^T (n-major) and v (d-major), +bias
// MODE 1: proj -> d_out = acc + bias + x (residual)
template <int MODE>
__global__ __launch_bounds__(256) void gemm_kernel(
    const __bf16* __restrict__ A, const __bf16* __restrict__ Bm,
    const float* __restrict__ bias, const float* __restrict__ xres,
    __bf16* __restrict__ q_t, __bf16* __restrict__ k_t, __bf16* __restrict__ v,
    float* __restrict__ outp) {
  __shared__ __bf16 sA[128 * 64];
  __shared__ __bf16 sB[128 * 64];
  const int tid = threadIdx.x;
  const int lane = tid & 63;
  const int wid = tid >> 6;
  const int wm = wid >> 1, wn = wid & 1;
  const int row_a = blockIdx.x * 128, row_b = blockIdx.y * 128;
  const int l15 = lane & 15, lg = lane >> 4;
  f32x4 acc[4][4] = {};
  const int sr = tid >> 3;
  const int sc = tid & 7;
  for (int k0 = 0; k0 < CC; k0 += 64) {
#pragma unroll
    for (int j = 0; j < 4; ++j) {
      int r = j * 32 + sr;
      int cl = sc ^ (r & 7);  // inverse-swizzled SOURCE, linear LDS dest
      GL2LDS(A + (size_t)(row_a + r) * CC + k0 + cl * 8, sA + j * 2048 + tid * 8);
      GL2LDS(Bm + (size_t)(row_b + r) * CC + k0 + cl * 8, sB + j * 2048 + tid * 8);
    }
    __syncthreads();
#pragma unroll
    for (int kk = 0; kk < 2; ++kk) {
      bf16x8 af[4], bq[4];
#pragma unroll
      for (int i = 0; i < 4; ++i) {
        int ra = wm * 64 + i * 16 + l15;
        int ca = kk * 4 + lg;
        af[i] = *(const bf16x8*)&sA[ra * 64 + ((ca ^ (ra & 7)) * 8)];
        int rb = wn * 64 + i * 16 + l15;
        bq[i] = *(const bf16x8*)&sB[rb * 64 + ((ca ^ (rb & 7)) * 8)];
      }
#pragma unroll
      for (int mi = 0; mi < 4; ++mi)
#pragma unroll
        for (int nj = 0; nj < 4; ++nj)
          acc[mi][nj] = MFMA(af[mi], bq[nj], acc[mi][nj]);
    }
    __syncthreads();
  }
#pragma unroll
  for (int mi = 0; mi < 4; ++mi) {
    const int o0 = row_a + wm * 64 + mi * 16 + (lg << 2);
    float b4[4];
#pragma unroll
    for (int r = 0; r < 4; ++r) b4[r] = bias[o0 + r];
#pragma unroll
    for (int nj = 0; nj < 4; ++nj) {
      const int bn = row_b + wn * 64 + nj * 16 + l15;
      const int b_ = bn >> 12, n_ = bn & 4095;
      if constexpr (MODE == 0) {
        const int which = o0 >> 9, hh = (o0 >> 6) & 7, d0 = o0 & 63;
        if (which < 2) {
          const float qs = (which == 0) ? QSCALE : 1.0f;
          __bf16* dst = (which ? k_t : q_t) + (((size_t)b_ * NH + hh) * NNP + n_) * HD + d0;
          bf16x4 pk;
#pragma unroll
          for (int r = 0; r < 4; ++r) pk[r] = (__bf16)((acc[mi][nj][r] + b4[r]) * qs);
          *(bf16x4*)dst = pk;
        } else {
#pragma unroll
          for (int r = 0; r < 4; ++r)
            v[(((size_t)b_ * NH + hh) * HD + d0 + r) * NNP + n_] =
                (__bf16)(acc[mi][nj][r] + b4[r]);
        }
      } else {
        const size_t base = ((size_t)b_ * CC + o0) * NNP + n_;
#pragma unroll
        for (int r = 0; r < 4; ++r)
          outp[base + (size_t)r * NNP] = acc[mi][nj][r] + b4[r] + xres[base + (size_t)r * NNP];
      }
    }
  }
}

// ---------------- flash attention, 32x32 swapped-QK, no LDS ----------------
// wave owns 32 queries (col n = lane&31). S^T = mfma32(K, Q). Softmax fully
// in-register; P -> PV B-operand via bf16 pack + __shfl_xor(32); V d-major.
// R4: K register double-buffer prefetch, early V issue, XCD swizzle, (256,2).
struct KBuf {
  bf16x8 k[8];
};

__global__ __launch_bounds__(256, 2) void attn_kernel(const __bf16* __restrict__ q_t,
                                                      const __bf16* __restrict__ k_t,
                                                      const __bf16* __restrict__ vm,
                                                      __bf16* __restrict__ o_t) {
  const int blk = blockIdx.x;  // B*NH*32; bh = blk&15 -> same head pins to one XCD
  const int bh = blk & 15, qt = blk >> 4;
  const int tid = threadIdx.x, lane = tid & 63, wid = tid >> 6;
  const int l31 = lane & 31, hi = lane >> 5;
  const int n0 = qt * 128 + wid * 32;
  const __bf16* qp = q_t + ((size_t)bh * NNP + n0) * HD;
  const __bf16* kp = k_t + (size_t)bh * NNP * HD;
  const __bf16* vp = vm + (size_t)bh * HD * NNP;
  bf16x8 qf[4];  // B-operand: col n = l31, k = d = c*16 + hi*8 + j
#pragma unroll
  for (int c = 0; c < 4; ++c) qf[c] = *(const bf16x8*)&qp[l31 * HD + c * 16 + hi * 8];
  f32x16 oa0 = {}, oa1 = {};  // O^T tiles: d 0..31 / 32..63, col n = l31
  float mrow = -1e30f, lrow = 0.f;

  auto PFK = [&](KBuf& b, int m) {
#pragma unroll
    for (int c = 0; c < 4; ++c) {
      b.k[c] = *(const bf16x8*)&kp[(size_t)(m + l31) * HD + c * 16 + hi * 8];
      b.k[4 + c] = *(const bf16x8*)&kp[(size_t)(m + 32 + l31) * HD + c * 16 + hi * 8];
    }
  };

  auto STEP = [&](const KBuf& kbf, int m0) {
    // early V issue: consumed ~QK+softmax later
    bf16x8 vf[8];
#pragma unroll
    for (int g = 0; g < 2; ++g)
#pragma unroll
      for (int mc = 0; mc < 2; ++mc) {
        const int mb = m0 + g * 32 + mc * 16 + hi * 8;
        vf[g * 2 + mc] = *(const bf16x8*)&vp[(size_t)l31 * NNP + mb];
        vf[4 + g * 2 + mc] = *(const bf16x8*)&vp[(size_t)(32 + l31) * NNP + mb];
      }
    f32x16 s0 = {}, s1 = {};
#pragma unroll
    for (int c = 0; c < 4; ++c) {
      s0 = MFMA32(kbf.k[c], qf[c], s0);
      s1 = MFMA32(kbf.k[4 + c], qf[c], s1);
    }
    float mx[8];
#pragma unroll
    for (int r = 0; r < 8; ++r)
      mx[r] = fmaxf(fmaxf(s0[r], s0[r + 8]), fmaxf(s1[r], s1[r + 8]));
#pragma unroll
    for (int st = 4; st >= 1; st >>= 1)
#pragma unroll
      for (int r = 0; r < 4; ++r)
        if (r < st) mx[r] = fmaxf(mx[r], mx[r + st]);
    float tmax = mx[0];
    tmax = fmaxf(tmax, __shfl_xor(tmax, 32));
    const float mnew = fmaxf(mrow, tmax);
    const float alpha = exp2f(mrow - mnew);
    lrow *= alpha;
#pragma unroll
    for (int r = 0; r < 16; ++r) {
      oa0[r] *= alpha;
      oa1[r] *= alpha;
    }
    mrow = mnew;
    float psum = 0.f;
#pragma unroll
    for (int r = 0; r < 16; ++r) {
      s0[r] = exp2f(s0[r] - mrow);
      s1[r] = exp2f(s1[r] - mrow);
      psum += s0[r] + s1[r];
    }
    psum += __shfl_xor(psum, 32);
    lrow += psum;
    // pack P -> PV B-fragments (k-rows exchanged with lane^32 via shfl)
#pragma unroll
    for (int g = 0; g < 2; ++g) {
      unsigned u[8], pu[8];
#pragma unroll
      for (int i = 0; i < 8; ++i) {
        float a = (g == 0) ? s0[2 * i] : s1[2 * i];
        float b = (g == 0) ? s0[2 * i + 1] : s1[2 * i + 1];
        u[i] = pkcast(a, b);
      }
#pragma unroll
      for (int i = 0; i < 8; ++i) pu[i] = (unsigned)__shfl_xor((int)u[i], 32);
      union U {
        unsigned u[4];
        bf16x8 v;
      };
      U pf0, pf1;
      pf0.u[0] = hi ? pu[2] : u[0];
      pf0.u[1] = hi ? pu[3] : u[1];
      pf0.u[2] = hi ? u[2] : pu[0];
      pf0.u[3] = hi ? u[3] : pu[1];
      pf1.u[0] = hi ? pu[6] : u[4];
      pf1.u[1] = hi ? pu[7] : u[5];
      pf1.u[2] = hi ? u[6] : pu[4];
      pf1.u[3] = hi ? u[7] : pu[5];
#pragma unroll
      for (int mc = 0; mc < 2; ++mc) {
        bf16x8 pf = mc ? pf1.v : pf0.v;
        oa0 = MFMA32(vf[g * 2 + mc], pf, oa0);
        oa1 = MFMA32(vf[4 + g * 2 + mc], pf, oa1);
      }
    }
  };

  KBuf ka, kb;
  PFK(ka, 0);
  for (int m0 = 0; m0 < NNP; m0 += 128) {
    PFK(kb, m0 + 64);
    STEP(ka, m0);
    PFK(ka, (m0 + 128) & (NNP - 1));  // last one wraps harmlessly
    STEP(kb, m0 + 64);
  }

  const float invl = 1.f / lrow;
  const int b_ = bh >> 3, hh = bh & 7;
  __bf16* op = o_t + ((size_t)b_ * NNP + n0 + l31) * CC + hh * HD;
#pragma unroll
  for (int g = 0; g < 4; ++g) {  // d = 8g + 4hi + r (tile0), +32 (tile1)
    bf16x4 p0, p1;
#pragma unroll
    for (int r = 0; r < 4; ++r) {
      p0[r] = (__bf16)(oa0[4 * g + r] * invl);
      p1[r] = (__bf16)(oa1[4 * g + r] * invl);
    }
    *(bf16x4*)(op + 8 * g + 4 * hi) = p0;
    *(bf16x4*)(op + 32 + 8 * g + 4 * hi) = p1;
  }
}

extern "C" void kernel_launch(void* const* d_in, const int* in_sizes, int n_in,
                              void* d_out, int out_size, void* d_ws, size_t ws_size,
                              hipStream_t stream) {
  const float* x = (const float*)d_in[0];
  const float* gn_w = (const float*)d_in[1];
  const float* gn_b = (const float*)d_in[2];
  const float* qkv_w = (const float*)d_in[3];
  const float* qkv_b = (const float*)d_in[4];
  const float* proj_w = (const float*)d_in[5];
  const float* proj_b = (const float*)d_in[6];
  float* out = (float*)d_out;
  char* ws = (char*)d_ws;
  const size_t SZ = (size_t)BB * NNP * CC * 2;  // 8 MiB per bf16 (B,N,C) tensor
  __bf16* h_t = (__bf16*)(ws);
  __bf16* q_t = (__bf16*)(ws + SZ);
  __bf16* k_t = (__bf16*)(ws + 2 * SZ);
  __bf16* v = (__bf16*)(ws + 3 * SZ);
  __bf16* o_t = (__bf16*)(ws + 4 * SZ);
  __bf16* wq = (__bf16*)(ws + 5 * SZ);
  __bf16* wp = (__bf16*)(ws + 5 * SZ + (size_t)3 * CC * CC * 2);

  cvt_kernel<<<dim3(1024), dim3(256), 0, stream>>>(qkv_w, proj_w, wq, wp);
  gn_kernel<<<dim3(64), dim3(256), 0, stream>>>(x, gn_w, gn_b, h_t);
  gemm_kernel<0><<<dim3(12, 64), dim3(256), 0, stream>>>(wq, h_t, qkv_b, nullptr, q_t, k_t,
                                                         v, nullptr);
  attn_kernel<<<dim3(BB * NH * 32), dim3(256), 0, stream>>>(q_t, k_t, v, o_t);
  gemm_kernel<1><<<dim3(4, 64), dim3(256), 0, stream>>>(wp, o_t, proj_b, x, nullptr, nullptr,
                                                        nullptr, out);
}